// Round 1
// baseline (1075.889 us; speedup 1.0000x reference)
//
#include <hip/hip_runtime.h>

// LightGCN 3-hop propagation, D=64.
// Structure:
//   init_out:   out[0..2] = 0.25*embeds[idx]   (hop-0 contribution to pooled)
//               out[3..5] = embeds[idx]
//   per layer:  memset(agg_out); spmm_atomic(x -> agg_out); gather_add(agg_out)
// Only two N*64 ping-pong buffers in d_ws; no full acc buffer needed since
// pooled is only read at the gathered indices.

__global__ __launch_bounds__(256) void spmm_atomic_k(
    const int* __restrict__ rows, const int* __restrict__ cols,
    const float* __restrict__ vals, const float* __restrict__ x,
    float* __restrict__ y, int E)
{
    long tid = (long)blockIdx.x * blockDim.x + threadIdx.x;
    int e = (int)(tid >> 6);          // one 64-lane wave per edge
    if (e >= E) return;
    int d = (int)(tid & 63);          // lane = feature dim
    int r = rows[e];                  // wave-uniform loads
    int c = cols[e];
    float v = vals[e];
    float xv = x[(long)c * 64 + d];   // coalesced 256B gather
    atomicAdd(y + (long)r * 64 + d, v * xv);
}

__global__ __launch_bounds__(256) void init_out_k(
    const float* __restrict__ emb, const int* __restrict__ n0,
    const int* __restrict__ n1, const int* __restrict__ n2,
    float* __restrict__ out, int B)
{
    int tid = blockIdx.x * blockDim.x + threadIdx.x;
    int total = 3 * B * 64;
    if (tid >= total) return;
    int arr = tid / (B * 64);
    int rem = tid - arr * (B * 64);
    int b = rem >> 6;
    int d = rem & 63;
    const int* __restrict__ idx = (arr == 0) ? n0 : ((arr == 1) ? n1 : n2);
    float v = emb[(long)idx[b] * 64 + d];
    out[(long)arr * B * 64 + rem] = 0.25f * v;        // pooled: hop-0 term
    out[(long)(arr + 3) * B * 64 + rem] = v;          // raw embeds gather
}

__global__ __launch_bounds__(256) void gather_add_k(
    const float* __restrict__ agg, const int* __restrict__ n0,
    const int* __restrict__ n1, const int* __restrict__ n2,
    float* __restrict__ out, int B)
{
    int tid = blockIdx.x * blockDim.x + threadIdx.x;
    int total = 3 * B * 64;
    if (tid >= total) return;
    int arr = tid / (B * 64);
    int rem = tid - arr * (B * 64);
    int b = rem >> 6;
    int d = rem & 63;
    const int* __restrict__ idx = (arr == 0) ? n0 : ((arr == 1) ? n1 : n2);
    out[(long)arr * B * 64 + rem] += 0.25f * agg[(long)idx[b] * 64 + d];
}

extern "C" void kernel_launch(void* const* d_in, const int* in_sizes, int n_in,
                              void* d_out, int out_size, void* d_ws, size_t ws_size,
                              hipStream_t stream)
{
    const float* emb  = (const float*)d_in[0];
    const int*   rows = (const int*)d_in[1];
    const int*   cols = (const int*)d_in[2];
    const float* vals = (const float*)d_in[3];
    const int*   node = (const int*)d_in[4];
    const int*   pos  = (const int*)d_in[5];
    const int*   neg  = (const int*)d_in[6];
    float* out = (float*)d_out;

    const int E = in_sizes[1];
    const int B = in_sizes[4];
    const int N = in_sizes[0] / 64;
    const size_t nd = (size_t)N * 64;

    float* aggA = (float*)d_ws;          // [N,64]
    float* aggB = aggA + nd;             // [N,64]

    const int gtotal  = 3 * B * 64;
    const int gblocks = (gtotal + 255) / 256;
    const int sblocks = (E + 3) / 4;     // E*64 threads / 256

    init_out_k<<<gblocks, 256, 0, stream>>>(emb, node, pos, neg, out, B);

    // layer 1: embeds -> aggA
    hipMemsetAsync(aggA, 0, nd * sizeof(float), stream);
    spmm_atomic_k<<<sblocks, 256, 0, stream>>>(rows, cols, vals, emb, aggA, E);
    gather_add_k<<<gblocks, 256, 0, stream>>>(aggA, node, pos, neg, out, B);

    // layer 2: aggA -> aggB
    hipMemsetAsync(aggB, 0, nd * sizeof(float), stream);
    spmm_atomic_k<<<sblocks, 256, 0, stream>>>(rows, cols, vals, aggA, aggB, E);
    gather_add_k<<<gblocks, 256, 0, stream>>>(aggB, node, pos, neg, out, B);

    // layer 3: aggB -> aggA
    hipMemsetAsync(aggA, 0, nd * sizeof(float), stream);
    spmm_atomic_k<<<sblocks, 256, 0, stream>>>(rows, cols, vals, aggB, aggA, E);
    gather_add_k<<<gblocks, 256, 0, stream>>>(aggA, node, pos, neg, out, B);
}

// Round 2
// 640.026 us; speedup vs baseline: 1.6810x; 1.6810x over previous
//
#include <hip/hip_runtime.h>

// LightGCN 3-hop propagation, D=64, fp32.
// R2: on-the-fly CSR build (hist -> scan -> scatter), then atomic-free
// row-parallel spmm: one wave per row, lane = feature dim, register acc,
// single coalesced 256B store per row. Kills the 400MB/dispatch atomic
// write-through seen in R1 counters.

#define NB_SCAN(n) (((n) + 255) / 256)

__global__ __launch_bounds__(256) void hist_k(
    const int* __restrict__ rows, int* __restrict__ counts, int E)
{
    int e = blockIdx.x * blockDim.x + threadIdx.x;
    if (e < E) atomicAdd(&counts[rows[e]], 1);
}

__global__ __launch_bounds__(256) void block_sums_k(
    const int* __restrict__ counts, int* __restrict__ bsums, int N)
{
    __shared__ int sm[256];
    int i = blockIdx.x * 256 + threadIdx.x;
    sm[threadIdx.x] = (i < N) ? counts[i] : 0;
    __syncthreads();
    for (int off = 128; off > 0; off >>= 1) {
        if (threadIdx.x < off) sm[threadIdx.x] += sm[threadIdx.x + off];
        __syncthreads();
    }
    if (threadIdx.x == 0) bsums[blockIdx.x] = sm[0];
}

__global__ __launch_bounds__(512) void scan_bsums_k(
    const int* __restrict__ bsums, int* __restrict__ bprefix, int nb)
{
    __shared__ int sm[512];
    int t = threadIdx.x;
    int v = (t < nb) ? bsums[t] : 0;
    sm[t] = v;
    __syncthreads();
    for (int off = 1; off < 512; off <<= 1) {
        int add = (t >= off) ? sm[t - off] : 0;
        __syncthreads();
        sm[t] += add;
        __syncthreads();
    }
    if (t < nb) bprefix[t] = sm[t] - v;   // exclusive prefix of block sums
}

__global__ __launch_bounds__(256) void scan_counts_k(
    const int* __restrict__ counts, const int* __restrict__ bprefix,
    int* __restrict__ row_start, int* __restrict__ cursor, int N)
{
    __shared__ int sm[256];
    int i = blockIdx.x * 256 + threadIdx.x;
    int c = (i < N) ? counts[i] : 0;
    sm[threadIdx.x] = c;
    __syncthreads();
    for (int off = 1; off < 256; off <<= 1) {
        int add = (threadIdx.x >= off) ? sm[threadIdx.x - off] : 0;
        __syncthreads();
        sm[threadIdx.x] += add;
        __syncthreads();
    }
    if (i < N) {
        int excl = sm[threadIdx.x] - c + bprefix[blockIdx.x];
        row_start[i] = excl;
        cursor[i]    = excl;
        if (i == N - 1) row_start[N] = excl + c;   // == E
    }
}

__global__ __launch_bounds__(256) void scatter_k(
    const int* __restrict__ rows, const int* __restrict__ cols,
    const float* __restrict__ vals, int* __restrict__ cursor,
    int* __restrict__ cols_s, float* __restrict__ vals_s, int E)
{
    int e = blockIdx.x * blockDim.x + threadIdx.x;
    if (e >= E) return;
    int pos = atomicAdd(&cursor[rows[e]], 1);
    cols_s[pos] = cols[e];
    vals_s[pos] = vals[e];
}

// one wave per row; lane = feature dim
__global__ __launch_bounds__(256) void spmm_csr_k(
    const int* __restrict__ row_start, const int* __restrict__ cols_s,
    const float* __restrict__ vals_s, const float* __restrict__ x,
    float* __restrict__ y, int N)
{
    long tid = (long)blockIdx.x * blockDim.x + threadIdx.x;
    int r = (int)(tid >> 6);
    if (r >= N) return;
    int d = (int)(tid & 63);
    int s = row_start[r];
    int e = row_start[r + 1];
    float acc = 0.0f;
    int j = s;
    if (j < e) {
        int   c = cols_s[j];
        float v = vals_s[j];
        for (; j + 1 < e; ++j) {              // 2-deep pipeline: prefetch next edge
            int   cn = cols_s[j + 1];
            float vn = vals_s[j + 1];
            acc += v * x[(long)c * 64 + d];
            c = cn; v = vn;
        }
        acc += v * x[(long)c * 64 + d];
    }
    y[(long)r * 64 + d] = acc;
}

__global__ __launch_bounds__(256) void init_out_k(
    const float* __restrict__ emb, const int* __restrict__ n0,
    const int* __restrict__ n1, const int* __restrict__ n2,
    float* __restrict__ out, int B)
{
    int tid = blockIdx.x * blockDim.x + threadIdx.x;
    int total = 3 * B * 64;
    if (tid >= total) return;
    int arr = tid / (B * 64);
    int rem = tid - arr * (B * 64);
    int b = rem >> 6;
    int d = rem & 63;
    const int* __restrict__ idx = (arr == 0) ? n0 : ((arr == 1) ? n1 : n2);
    float v = emb[(long)idx[b] * 64 + d];
    out[(long)arr * B * 64 + rem] = 0.25f * v;   // hop-0 term of pooled
    out[(long)(arr + 3) * B * 64 + rem] = v;     // raw embeds gather
}

__global__ __launch_bounds__(256) void gather_add_k(
    const float* __restrict__ agg, const int* __restrict__ n0,
    const int* __restrict__ n1, const int* __restrict__ n2,
    float* __restrict__ out, int B)
{
    int tid = blockIdx.x * blockDim.x + threadIdx.x;
    int total = 3 * B * 64;
    if (tid >= total) return;
    int arr = tid / (B * 64);
    int rem = tid - arr * (B * 64);
    int b = rem >> 6;
    int d = rem & 63;
    const int* __restrict__ idx = (arr == 0) ? n0 : ((arr == 1) ? n1 : n2);
    out[(long)arr * B * 64 + rem] += 0.25f * agg[(long)idx[b] * 64 + d];
}

extern "C" void kernel_launch(void* const* d_in, const int* in_sizes, int n_in,
                              void* d_out, int out_size, void* d_ws, size_t ws_size,
                              hipStream_t stream)
{
    const float* emb  = (const float*)d_in[0];
    const int*   rows = (const int*)d_in[1];
    const int*   cols = (const int*)d_in[2];
    const float* vals = (const float*)d_in[3];
    const int*   node = (const int*)d_in[4];
    const int*   pos  = (const int*)d_in[5];
    const int*   neg  = (const int*)d_in[6];
    float* out = (float*)d_out;

    const int E = in_sizes[1];
    const int B = in_sizes[4];
    const int N = in_sizes[0] / 64;
    const size_t nd = (size_t)N * 64;
    const int nb = NB_SCAN(N);

    // workspace layout
    float* aggA      = (float*)d_ws;               // N*64
    float* aggB      = aggA + nd;                  // N*64
    int*   cols_s    = (int*)(aggB + nd);          // E
    float* vals_s    = (float*)(cols_s + E);       // E
    int*   counts    = (int*)(vals_s + E);         // N
    int*   row_start = counts + N;                 // N+1
    int*   cursor    = row_start + N + 1;          // N
    int*   bsums     = cursor + N;                 // nb
    int*   bprefix   = bsums + nb;                 // nb

    const int gtotal  = 3 * B * 64;
    const int gblocks = (gtotal + 255) / 256;
    const int eblocks = (E + 255) / 256;
    const int rblocks = (N * 64 + 255) / 256;      // one wave per row

    // independent of CSR build
    init_out_k<<<gblocks, 256, 0, stream>>>(emb, node, pos, neg, out, B);

    // ---- CSR build (every call; no cross-call state) ----
    hipMemsetAsync(counts, 0, (size_t)N * sizeof(int), stream);
    hist_k<<<eblocks, 256, 0, stream>>>(rows, counts, E);
    block_sums_k<<<nb, 256, 0, stream>>>(counts, bsums, N);
    scan_bsums_k<<<1, 512, 0, stream>>>(bsums, bprefix, nb);
    scan_counts_k<<<nb, 256, 0, stream>>>(counts, bprefix, row_start, cursor, N);
    scatter_k<<<eblocks, 256, 0, stream>>>(rows, cols, vals, cursor, cols_s, vals_s, E);

    // ---- 3 propagation hops, atomic-free ----
    spmm_csr_k<<<rblocks, 256, 0, stream>>>(row_start, cols_s, vals_s, emb, aggA, N);
    gather_add_k<<<gblocks, 256, 0, stream>>>(aggA, node, pos, neg, out, B);

    spmm_csr_k<<<rblocks, 256, 0, stream>>>(row_start, cols_s, vals_s, aggA, aggB, N);
    gather_add_k<<<gblocks, 256, 0, stream>>>(aggB, node, pos, neg, out, B);

    spmm_csr_k<<<rblocks, 256, 0, stream>>>(row_start, cols_s, vals_s, aggB, aggA, N);
    gather_add_k<<<gblocks, 256, 0, stream>>>(aggA, node, pos, neg, out, B);
}

// Round 3
// 323.785 us; speedup vs baseline: 3.3228x; 1.9767x over previous
//
#include <hip/hip_runtime.h>

// LightGCN 3-hop propagation, D=64, fp32.
// R3: (1) spmm unrolled x4 with 4 independent accumulators (latency hiding —
// R2 counters showed latency-bound: VALUBusy 17%, BW 18%, occ 74%);
// (2) CSR build: rank fused into hist (one atomic pass), (col,val) packed
// into int2 (one 8B scattered store; one 8B edge load in spmm).

#define NB_SCAN(n) (((n) + 255) / 256)

__global__ __launch_bounds__(256) void hist_rank_k(
    const int* __restrict__ rows, int* __restrict__ counts,
    int* __restrict__ rank, int E)
{
    int e = blockIdx.x * blockDim.x + threadIdx.x;
    if (e < E) rank[e] = atomicAdd(&counts[rows[e]], 1);
}

__global__ __launch_bounds__(256) void block_sums_k(
    const int* __restrict__ counts, int* __restrict__ bsums, int N)
{
    __shared__ int sm[256];
    int i = blockIdx.x * 256 + threadIdx.x;
    sm[threadIdx.x] = (i < N) ? counts[i] : 0;
    __syncthreads();
    for (int off = 128; off > 0; off >>= 1) {
        if (threadIdx.x < off) sm[threadIdx.x] += sm[threadIdx.x + off];
        __syncthreads();
    }
    if (threadIdx.x == 0) bsums[blockIdx.x] = sm[0];
}

__global__ __launch_bounds__(512) void scan_bsums_k(
    const int* __restrict__ bsums, int* __restrict__ bprefix, int nb)
{
    __shared__ int sm[512];
    int t = threadIdx.x;
    int v = (t < nb) ? bsums[t] : 0;
    sm[t] = v;
    __syncthreads();
    for (int off = 1; off < 512; off <<= 1) {
        int add = (t >= off) ? sm[t - off] : 0;
        __syncthreads();
        sm[t] += add;
        __syncthreads();
    }
    if (t < nb) bprefix[t] = sm[t] - v;   // exclusive prefix of block sums
}

__global__ __launch_bounds__(256) void scan_counts_k(
    const int* __restrict__ counts, const int* __restrict__ bprefix,
    int* __restrict__ row_start, int N)
{
    __shared__ int sm[256];
    int i = blockIdx.x * 256 + threadIdx.x;
    int c = (i < N) ? counts[i] : 0;
    sm[threadIdx.x] = c;
    __syncthreads();
    for (int off = 1; off < 256; off <<= 1) {
        int add = (threadIdx.x >= off) ? sm[threadIdx.x - off] : 0;
        __syncthreads();
        sm[threadIdx.x] += add;
        __syncthreads();
    }
    if (i < N) {
        int excl = sm[threadIdx.x] - c + bprefix[blockIdx.x];
        row_start[i] = excl;
        if (i == N - 1) row_start[N] = excl + c;   // == E
    }
}

__global__ __launch_bounds__(256) void scatter_k(
    const int* __restrict__ rows, const int* __restrict__ cols,
    const float* __restrict__ vals, const int* __restrict__ rank,
    const int* __restrict__ row_start, int2* __restrict__ edges, int E)
{
    int e = blockIdx.x * blockDim.x + threadIdx.x;
    if (e >= E) return;
    int pos = row_start[rows[e]] + rank[e];
    edges[pos] = make_int2(cols[e], __float_as_int(vals[e]));  // one 8B store
}

// one wave per row; lane = feature dim; 4 independent gather chains
__global__ __launch_bounds__(256) void spmm_csr_k(
    const int* __restrict__ row_start, const int2* __restrict__ edges,
    const float* __restrict__ x, float* __restrict__ y, int N)
{
    long tid = (long)blockIdx.x * blockDim.x + threadIdx.x;
    int r = (int)(tid >> 6);
    if (r >= N) return;
    int d = (int)(tid & 63);
    int s = row_start[r];
    int e = row_start[r + 1];
    float a0 = 0.f, a1 = 0.f, a2 = 0.f, a3 = 0.f;
    int j = s;
    for (; j + 4 <= e; j += 4) {
        int2 e0 = edges[j];
        int2 e1 = edges[j + 1];
        int2 e2 = edges[j + 2];
        int2 e3 = edges[j + 3];
        a0 += __int_as_float(e0.y) * x[(long)e0.x * 64 + d];
        a1 += __int_as_float(e1.y) * x[(long)e1.x * 64 + d];
        a2 += __int_as_float(e2.y) * x[(long)e2.x * 64 + d];
        a3 += __int_as_float(e3.y) * x[(long)e3.x * 64 + d];
    }
    for (; j < e; ++j) {
        int2 e0 = edges[j];
        a0 += __int_as_float(e0.y) * x[(long)e0.x * 64 + d];
    }
    y[(long)r * 64 + d] = (a0 + a1) + (a2 + a3);
}

__global__ __launch_bounds__(256) void init_out_k(
    const float* __restrict__ emb, const int* __restrict__ n0,
    const int* __restrict__ n1, const int* __restrict__ n2,
    float* __restrict__ out, int B)
{
    int tid = blockIdx.x * blockDim.x + threadIdx.x;
    int total = 3 * B * 64;
    if (tid >= total) return;
    int arr = tid / (B * 64);
    int rem = tid - arr * (B * 64);
    int b = rem >> 6;
    int d = rem & 63;
    const int* __restrict__ idx = (arr == 0) ? n0 : ((arr == 1) ? n1 : n2);
    float v = emb[(long)idx[b] * 64 + d];
    out[(long)arr * B * 64 + rem] = 0.25f * v;   // hop-0 term of pooled
    out[(long)(arr + 3) * B * 64 + rem] = v;     // raw embeds gather
}

__global__ __launch_bounds__(256) void gather_add_k(
    const float* __restrict__ agg, const int* __restrict__ n0,
    const int* __restrict__ n1, const int* __restrict__ n2,
    float* __restrict__ out, int B)
{
    int tid = blockIdx.x * blockDim.x + threadIdx.x;
    int total = 3 * B * 64;
    if (tid >= total) return;
    int arr = tid / (B * 64);
    int rem = tid - arr * (B * 64);
    int b = rem >> 6;
    int d = rem & 63;
    const int* __restrict__ idx = (arr == 0) ? n0 : ((arr == 1) ? n1 : n2);
    out[(long)arr * B * 64 + rem] += 0.25f * agg[(long)idx[b] * 64 + d];
}

extern "C" void kernel_launch(void* const* d_in, const int* in_sizes, int n_in,
                              void* d_out, int out_size, void* d_ws, size_t ws_size,
                              hipStream_t stream)
{
    const float* emb  = (const float*)d_in[0];
    const int*   rows = (const int*)d_in[1];
    const int*   cols = (const int*)d_in[2];
    const float* vals = (const float*)d_in[3];
    const int*   node = (const int*)d_in[4];
    const int*   pos  = (const int*)d_in[5];
    const int*   neg  = (const int*)d_in[6];
    float* out = (float*)d_out;

    const int E = in_sizes[1];
    const int B = in_sizes[4];
    const int N = in_sizes[0] / 64;
    const size_t nd = (size_t)N * 64;
    const int nb = NB_SCAN(N);

    // workspace layout
    float* aggA      = (float*)d_ws;               // N*64
    float* aggB      = aggA + nd;                  // N*64
    int2*  edges     = (int2*)(aggB + nd);         // E (8B each)
    int*   rank      = (int*)(edges + E);          // E
    int*   counts    = rank + E;                   // N
    int*   row_start = counts + N;                 // N+1
    int*   bsums     = row_start + N + 1;          // nb
    int*   bprefix   = bsums + nb;                 // nb

    const int gtotal  = 3 * B * 64;
    const int gblocks = (gtotal + 255) / 256;
    const int eblocks = (E + 255) / 256;
    const int rblocks = (N * 64 + 255) / 256;      // one wave per row

    // independent of CSR build
    init_out_k<<<gblocks, 256, 0, stream>>>(emb, node, pos, neg, out, B);

    // ---- CSR build ----
    hipMemsetAsync(counts, 0, (size_t)N * sizeof(int), stream);
    hist_rank_k<<<eblocks, 256, 0, stream>>>(rows, counts, rank, E);
    block_sums_k<<<nb, 256, 0, stream>>>(counts, bsums, N);
    scan_bsums_k<<<1, 512, 0, stream>>>(bsums, bprefix, nb);
    scan_counts_k<<<nb, 256, 0, stream>>>(counts, bprefix, row_start, N);
    scatter_k<<<eblocks, 256, 0, stream>>>(rows, cols, vals, rank, row_start, edges, E);

    // ---- 3 propagation hops, atomic-free ----
    spmm_csr_k<<<rblocks, 256, 0, stream>>>(row_start, edges, emb, aggA, N);
    gather_add_k<<<gblocks, 256, 0, stream>>>(aggA, node, pos, neg, out, B);

    spmm_csr_k<<<rblocks, 256, 0, stream>>>(row_start, edges, aggA, aggB, N);
    gather_add_k<<<gblocks, 256, 0, stream>>>(aggB, node, pos, neg, out, B);

    spmm_csr_k<<<rblocks, 256, 0, stream>>>(row_start, edges, aggB, aggA, N);
    gather_add_k<<<gblocks, 256, 0, stream>>>(aggA, node, pos, neg, out, B);
}

// Round 4
// 284.407 us; speedup vs baseline: 3.7829x; 1.1385x over previous
//
#include <hip/hip_runtime.h>

// LightGCN 3-hop propagation, D=64, fp32.
// R4: spmm with (a) wave-uniform row index via readfirstlane so the edge
// stream goes through scalar loads (s_load_dwordx16 merges 8 edges), keeping
// the vector memory pipe exclusively for x-gathers; (b) unroll x8 = 8
// independent gather chains in flight. R3 counters: VALUBusy 30%, fetch BW
// 36% peak, occ 72% -> still latency-bound, MLP is the lever.

#define NB_SCAN(n) (((n) + 255) / 256)

__global__ __launch_bounds__(256) void hist_rank_k(
    const int* __restrict__ rows, int* __restrict__ counts,
    int* __restrict__ rank, int E)
{
    int e = blockIdx.x * blockDim.x + threadIdx.x;
    if (e < E) rank[e] = atomicAdd(&counts[rows[e]], 1);
}

__global__ __launch_bounds__(256) void block_sums_k(
    const int* __restrict__ counts, int* __restrict__ bsums, int N)
{
    __shared__ int sm[256];
    int i = blockIdx.x * 256 + threadIdx.x;
    sm[threadIdx.x] = (i < N) ? counts[i] : 0;
    __syncthreads();
    for (int off = 128; off > 0; off >>= 1) {
        if (threadIdx.x < off) sm[threadIdx.x] += sm[threadIdx.x + off];
        __syncthreads();
    }
    if (threadIdx.x == 0) bsums[blockIdx.x] = sm[0];
}

__global__ __launch_bounds__(512) void scan_bsums_k(
    const int* __restrict__ bsums, int* __restrict__ bprefix, int nb)
{
    __shared__ int sm[512];
    int t = threadIdx.x;
    int v = (t < nb) ? bsums[t] : 0;
    sm[t] = v;
    __syncthreads();
    for (int off = 1; off < 512; off <<= 1) {
        int add = (t >= off) ? sm[t - off] : 0;
        __syncthreads();
        sm[t] += add;
        __syncthreads();
    }
    if (t < nb) bprefix[t] = sm[t] - v;   // exclusive prefix of block sums
}

__global__ __launch_bounds__(256) void scan_counts_k(
    const int* __restrict__ counts, const int* __restrict__ bprefix,
    int* __restrict__ row_start, int N)
{
    __shared__ int sm[256];
    int i = blockIdx.x * 256 + threadIdx.x;
    int c = (i < N) ? counts[i] : 0;
    sm[threadIdx.x] = c;
    __syncthreads();
    for (int off = 1; off < 256; off <<= 1) {
        int add = (threadIdx.x >= off) ? sm[threadIdx.x - off] : 0;
        __syncthreads();
        sm[threadIdx.x] += add;
        __syncthreads();
    }
    if (i < N) {
        int excl = sm[threadIdx.x] - c + bprefix[blockIdx.x];
        row_start[i] = excl;
        if (i == N - 1) row_start[N] = excl + c;   // == E
    }
}

__global__ __launch_bounds__(256) void scatter_k(
    const int* __restrict__ rows, const int* __restrict__ cols,
    const float* __restrict__ vals, const int* __restrict__ rank,
    const int* __restrict__ row_start, int2* __restrict__ edges, int E)
{
    int e = blockIdx.x * blockDim.x + threadIdx.x;
    if (e >= E) return;
    int pos = row_start[rows[e]] + rank[e];
    edges[pos] = make_int2(cols[e], __float_as_int(vals[e]));  // one 8B store
}

// one wave per row; lane = feature dim; edge stream on the SCALAR path;
// 8 independent gather chains in flight.
__global__ __launch_bounds__(256) void spmm_csr_k(
    const int* __restrict__ row_start, const int2* __restrict__ edges,
    const float* __restrict__ x, float* __restrict__ y, int N)
{
    int wid = __builtin_amdgcn_readfirstlane((int)(threadIdx.x >> 6)); // uniform
    int r = blockIdx.x * 4 + wid;
    if (r >= N) return;
    int d = (int)(threadIdx.x & 63);
    int s = row_start[r];      // uniform -> s_load
    int e = row_start[r + 1];
    float a0 = 0.f, a1 = 0.f, a2 = 0.f, a3 = 0.f;
    float a4 = 0.f, a5 = 0.f, a6 = 0.f, a7 = 0.f;
    int j = s;
    for (; j + 8 <= e; j += 8) {
        int2 e0 = edges[j];      // uniform addr -> s_load_dwordx16 merge
        int2 e1 = edges[j + 1];
        int2 e2 = edges[j + 2];
        int2 e3 = edges[j + 3];
        int2 e4 = edges[j + 4];
        int2 e5 = edges[j + 5];
        int2 e6 = edges[j + 6];
        int2 e7 = edges[j + 7];
        a0 += __int_as_float(e0.y) * x[(long)e0.x * 64 + d];
        a1 += __int_as_float(e1.y) * x[(long)e1.x * 64 + d];
        a2 += __int_as_float(e2.y) * x[(long)e2.x * 64 + d];
        a3 += __int_as_float(e3.y) * x[(long)e3.x * 64 + d];
        a4 += __int_as_float(e4.y) * x[(long)e4.x * 64 + d];
        a5 += __int_as_float(e5.y) * x[(long)e5.x * 64 + d];
        a6 += __int_as_float(e6.y) * x[(long)e6.x * 64 + d];
        a7 += __int_as_float(e7.y) * x[(long)e7.x * 64 + d];
    }
    for (; j + 4 <= e; j += 4) {
        int2 e0 = edges[j];
        int2 e1 = edges[j + 1];
        int2 e2 = edges[j + 2];
        int2 e3 = edges[j + 3];
        a0 += __int_as_float(e0.y) * x[(long)e0.x * 64 + d];
        a1 += __int_as_float(e1.y) * x[(long)e1.x * 64 + d];
        a2 += __int_as_float(e2.y) * x[(long)e2.x * 64 + d];
        a3 += __int_as_float(e3.y) * x[(long)e3.x * 64 + d];
    }
    for (; j < e; ++j) {
        int2 e0 = edges[j];
        a0 += __int_as_float(e0.y) * x[(long)e0.x * 64 + d];
    }
    y[(long)r * 64 + d] = ((a0 + a1) + (a2 + a3)) + ((a4 + a5) + (a6 + a7));
}

// out[0..2] = 0.25*emb[idx] (hop-0 term), out[3..5] = emb[idx]; float4 lanes
__global__ __launch_bounds__(256) void init_out_k(
    const float* __restrict__ emb, const int* __restrict__ n0,
    const int* __restrict__ n1, const int* __restrict__ n2,
    float* __restrict__ out, int B)
{
    int tid = blockIdx.x * blockDim.x + threadIdx.x;
    int total = 3 * B * 16;                 // float4 granularity
    if (tid >= total) return;
    int arr = tid / (B * 16);
    int rem = tid - arr * (B * 16);
    int b = rem >> 4;
    int d4 = rem & 15;
    const int* __restrict__ idx = (arr == 0) ? n0 : ((arr == 1) ? n1 : n2);
    float4 v = *(const float4*)(emb + (long)idx[b] * 64 + d4 * 4);
    float4 q = make_float4(0.25f * v.x, 0.25f * v.y, 0.25f * v.z, 0.25f * v.w);
    *(float4*)(out + (long)arr * B * 64 + (long)rem * 4) = q;
    *(float4*)(out + (long)(arr + 3) * B * 64 + (long)rem * 4) = v;
}

__global__ __launch_bounds__(256) void gather_add_k(
    const float* __restrict__ agg, const int* __restrict__ n0,
    const int* __restrict__ n1, const int* __restrict__ n2,
    float* __restrict__ out, int B)
{
    int tid = blockIdx.x * blockDim.x + threadIdx.x;
    int total = 3 * B * 16;
    if (tid >= total) return;
    int arr = tid / (B * 16);
    int rem = tid - arr * (B * 16);
    int b = rem >> 4;
    int d4 = rem & 15;
    const int* __restrict__ idx = (arr == 0) ? n0 : ((arr == 1) ? n1 : n2);
    float4 v = *(const float4*)(agg + (long)idx[b] * 64 + d4 * 4);
    float* o = out + (long)arr * B * 64 + (long)rem * 4;
    float4 cur = *(float4*)o;
    cur.x += 0.25f * v.x; cur.y += 0.25f * v.y;
    cur.z += 0.25f * v.z; cur.w += 0.25f * v.w;
    *(float4*)o = cur;
}

extern "C" void kernel_launch(void* const* d_in, const int* in_sizes, int n_in,
                              void* d_out, int out_size, void* d_ws, size_t ws_size,
                              hipStream_t stream)
{
    const float* emb  = (const float*)d_in[0];
    const int*   rows = (const int*)d_in[1];
    const int*   cols = (const int*)d_in[2];
    const float* vals = (const float*)d_in[3];
    const int*   node = (const int*)d_in[4];
    const int*   pos  = (const int*)d_in[5];
    const int*   neg  = (const int*)d_in[6];
    float* out = (float*)d_out;

    const int E = in_sizes[1];
    const int B = in_sizes[4];
    const int N = in_sizes[0] / 64;
    const size_t nd = (size_t)N * 64;
    const int nb = NB_SCAN(N);

    // workspace layout
    float* aggA      = (float*)d_ws;               // N*64
    float* aggB      = aggA + nd;                  // N*64
    int2*  edges     = (int2*)(aggB + nd);         // E (8B each)
    int*   rank      = (int*)(edges + E);          // E
    int*   counts    = rank + E;                   // N
    int*   row_start = counts + N;                 // N+1
    int*   bsums     = row_start + N + 1;          // nb
    int*   bprefix   = bsums + nb;                 // nb

    const int gtotal  = 3 * B * 16;
    const int gblocks = (gtotal + 255) / 256;
    const int eblocks = (E + 255) / 256;
    const int rblocks = (N + 3) / 4;               // 4 rows (waves) per block

    init_out_k<<<gblocks, 256, 0, stream>>>(emb, node, pos, neg, out, B);

    // ---- CSR build ----
    hipMemsetAsync(counts, 0, (size_t)N * sizeof(int), stream);
    hist_rank_k<<<eblocks, 256, 0, stream>>>(rows, counts, rank, E);
    block_sums_k<<<nb, 256, 0, stream>>>(counts, bsums, N);
    scan_bsums_k<<<1, 512, 0, stream>>>(bsums, bprefix, nb);
    scan_counts_k<<<nb, 256, 0, stream>>>(counts, bprefix, row_start, N);
    scatter_k<<<eblocks, 256, 0, stream>>>(rows, cols, vals, rank, row_start, edges, E);

    // ---- 3 propagation hops, atomic-free ----
    spmm_csr_k<<<rblocks, 256, 0, stream>>>(row_start, edges, emb, aggA, N);
    gather_add_k<<<gblocks, 256, 0, stream>>>(aggA, node, pos, neg, out, B);

    spmm_csr_k<<<rblocks, 256, 0, stream>>>(row_start, edges, aggA, aggB, N);
    gather_add_k<<<gblocks, 256, 0, stream>>>(aggB, node, pos, neg, out, B);

    spmm_csr_k<<<rblocks, 256, 0, stream>>>(row_start, edges, aggB, aggA, N);
    gather_add_k<<<gblocks, 256, 0, stream>>>(aggA, node, pos, neg, out, B);
}

// Round 5
// 247.362 us; speedup vs baseline: 4.3495x; 1.1498x over previous
//
#include <hip/hip_runtime.h>

// LightGCN 3-hop propagation, D=64.
// R5: propagate features in bf16 (threshold 0.4025 gives headroom; fp32
// accumulate inside spmm). Halves the spmm x-gather stream (the 181MB
// FETCH that dominates spmm) and the agg writes. Build unchanged this
// round: hist_rank (68us, atomic-throughput-bound) is next round's target.

#define NB_SCAN(n) (((n) + 255) / 256)

static __device__ __forceinline__ ushort f2bf(float f) {
    unsigned u = __float_as_uint(f);
    unsigned r = (u + 0x7fffu + ((u >> 16) & 1u)) >> 16;   // RNE
    return (ushort)r;
}
static __device__ __forceinline__ float bf2f(ushort b) {
    return __uint_as_float(((unsigned)b) << 16);
}

__global__ __launch_bounds__(256) void f2bf_k(
    const float* __restrict__ in, ushort* __restrict__ out, int n4)
{
    int i = blockIdx.x * blockDim.x + threadIdx.x;
    if (i >= n4) return;
    float4 v = *(const float4*)(in + (long)i * 4);
    ushort4 o;
    o.x = f2bf(v.x); o.y = f2bf(v.y); o.z = f2bf(v.z); o.w = f2bf(v.w);
    *(ushort4*)(out + (long)i * 4) = o;
}

__global__ __launch_bounds__(256) void hist_rank_k(
    const int* __restrict__ rows, int* __restrict__ counts,
    int* __restrict__ rank, int E)
{
    int e = blockIdx.x * blockDim.x + threadIdx.x;
    if (e < E) rank[e] = atomicAdd(&counts[rows[e]], 1);
}

__global__ __launch_bounds__(256) void block_sums_k(
    const int* __restrict__ counts, int* __restrict__ bsums, int N)
{
    __shared__ int sm[256];
    int i = blockIdx.x * 256 + threadIdx.x;
    sm[threadIdx.x] = (i < N) ? counts[i] : 0;
    __syncthreads();
    for (int off = 128; off > 0; off >>= 1) {
        if (threadIdx.x < off) sm[threadIdx.x] += sm[threadIdx.x + off];
        __syncthreads();
    }
    if (threadIdx.x == 0) bsums[blockIdx.x] = sm[0];
}

__global__ __launch_bounds__(512) void scan_bsums_k(
    const int* __restrict__ bsums, int* __restrict__ bprefix, int nb)
{
    __shared__ int sm[512];
    int t = threadIdx.x;
    int v = (t < nb) ? bsums[t] : 0;
    sm[t] = v;
    __syncthreads();
    for (int off = 1; off < 512; off <<= 1) {
        int add = (t >= off) ? sm[t - off] : 0;
        __syncthreads();
        sm[t] += add;
        __syncthreads();
    }
    if (t < nb) bprefix[t] = sm[t] - v;   // exclusive prefix of block sums
}

__global__ __launch_bounds__(256) void scan_counts_k(
    const int* __restrict__ counts, const int* __restrict__ bprefix,
    int* __restrict__ row_start, int N)
{
    __shared__ int sm[256];
    int i = blockIdx.x * 256 + threadIdx.x;
    int c = (i < N) ? counts[i] : 0;
    sm[threadIdx.x] = c;
    __syncthreads();
    for (int off = 1; off < 256; off <<= 1) {
        int add = (threadIdx.x >= off) ? sm[threadIdx.x - off] : 0;
        __syncthreads();
        sm[threadIdx.x] += add;
        __syncthreads();
    }
    if (i < N) {
        int excl = sm[threadIdx.x] - c + bprefix[blockIdx.x];
        row_start[i] = excl;
        if (i == N - 1) row_start[N] = excl + c;   // == E
    }
}

__global__ __launch_bounds__(256) void scatter_k(
    const int* __restrict__ rows, const int* __restrict__ cols,
    const float* __restrict__ vals, const int* __restrict__ rank,
    const int* __restrict__ row_start, int2* __restrict__ edges, int E)
{
    int e = blockIdx.x * blockDim.x + threadIdx.x;
    if (e >= E) return;
    int pos = row_start[rows[e]] + rank[e];
    edges[pos] = make_int2(cols[e], __float_as_int(vals[e]));  // one 8B store
}

// one wave per row; lane = feature dim; scalar edge stream; 8 gather chains.
// x is bf16 (ushort), accumulate fp32, store bf16.
__global__ __launch_bounds__(256) void spmm_csr_k(
    const int* __restrict__ row_start, const int2* __restrict__ edges,
    const ushort* __restrict__ x, ushort* __restrict__ y, int N)
{
    int wid = __builtin_amdgcn_readfirstlane((int)(threadIdx.x >> 6)); // uniform
    int r = blockIdx.x * 4 + wid;
    if (r >= N) return;
    int d = (int)(threadIdx.x & 63);
    int s = row_start[r];      // uniform -> s_load
    int e = row_start[r + 1];
    float a0 = 0.f, a1 = 0.f, a2 = 0.f, a3 = 0.f;
    float a4 = 0.f, a5 = 0.f, a6 = 0.f, a7 = 0.f;
    int j = s;
    for (; j + 8 <= e; j += 8) {
        int2 e0 = edges[j];
        int2 e1 = edges[j + 1];
        int2 e2 = edges[j + 2];
        int2 e3 = edges[j + 3];
        int2 e4 = edges[j + 4];
        int2 e5 = edges[j + 5];
        int2 e6 = edges[j + 6];
        int2 e7 = edges[j + 7];
        a0 += __int_as_float(e0.y) * bf2f(x[(long)e0.x * 64 + d]);
        a1 += __int_as_float(e1.y) * bf2f(x[(long)e1.x * 64 + d]);
        a2 += __int_as_float(e2.y) * bf2f(x[(long)e2.x * 64 + d]);
        a3 += __int_as_float(e3.y) * bf2f(x[(long)e3.x * 64 + d]);
        a4 += __int_as_float(e4.y) * bf2f(x[(long)e4.x * 64 + d]);
        a5 += __int_as_float(e5.y) * bf2f(x[(long)e5.x * 64 + d]);
        a6 += __int_as_float(e6.y) * bf2f(x[(long)e6.x * 64 + d]);
        a7 += __int_as_float(e7.y) * bf2f(x[(long)e7.x * 64 + d]);
    }
    for (; j + 4 <= e; j += 4) {
        int2 e0 = edges[j];
        int2 e1 = edges[j + 1];
        int2 e2 = edges[j + 2];
        int2 e3 = edges[j + 3];
        a0 += __int_as_float(e0.y) * bf2f(x[(long)e0.x * 64 + d]);
        a1 += __int_as_float(e1.y) * bf2f(x[(long)e1.x * 64 + d]);
        a2 += __int_as_float(e2.y) * bf2f(x[(long)e2.x * 64 + d]);
        a3 += __int_as_float(e3.y) * bf2f(x[(long)e3.x * 64 + d]);
    }
    for (; j < e; ++j) {
        int2 e0 = edges[j];
        a0 += __int_as_float(e0.y) * bf2f(x[(long)e0.x * 64 + d]);
    }
    float sum = ((a0 + a1) + (a2 + a3)) + ((a4 + a5) + (a6 + a7));
    y[(long)r * 64 + d] = f2bf(sum);
}

// out[0..2] = 0.25*emb[idx] (hop-0 term), out[3..5] = emb[idx]; float4 lanes
__global__ __launch_bounds__(256) void init_out_k(
    const float* __restrict__ emb, const int* __restrict__ n0,
    const int* __restrict__ n1, const int* __restrict__ n2,
    float* __restrict__ out, int B)
{
    int tid = blockIdx.x * blockDim.x + threadIdx.x;
    int total = 3 * B * 16;                 // float4 granularity
    if (tid >= total) return;
    int arr = tid / (B * 16);
    int rem = tid - arr * (B * 16);
    int b = rem >> 4;
    int d4 = rem & 15;
    const int* __restrict__ idx = (arr == 0) ? n0 : ((arr == 1) ? n1 : n2);
    float4 v = *(const float4*)(emb + (long)idx[b] * 64 + d4 * 4);
    float4 q = make_float4(0.25f * v.x, 0.25f * v.y, 0.25f * v.z, 0.25f * v.w);
    *(float4*)(out + (long)arr * B * 64 + (long)rem * 4) = q;
    *(float4*)(out + (long)(arr + 3) * B * 64 + (long)rem * 4) = v;
}

// pooled += 0.25 * agg_bf16[idx]
__global__ __launch_bounds__(256) void gather_add_k(
    const ushort* __restrict__ agg, const int* __restrict__ n0,
    const int* __restrict__ n1, const int* __restrict__ n2,
    float* __restrict__ out, int B)
{
    int tid = blockIdx.x * blockDim.x + threadIdx.x;
    int total = 3 * B * 16;
    if (tid >= total) return;
    int arr = tid / (B * 16);
    int rem = tid - arr * (B * 16);
    int b = rem >> 4;
    int d4 = rem & 15;
    const int* __restrict__ idx = (arr == 0) ? n0 : ((arr == 1) ? n1 : n2);
    ushort4 v = *(const ushort4*)(agg + (long)idx[b] * 64 + d4 * 4);
    float* o = out + (long)arr * B * 64 + (long)rem * 4;
    float4 cur = *(float4*)o;
    cur.x += 0.25f * bf2f(v.x); cur.y += 0.25f * bf2f(v.y);
    cur.z += 0.25f * bf2f(v.z); cur.w += 0.25f * bf2f(v.w);
    *(float4*)o = cur;
}

extern "C" void kernel_launch(void* const* d_in, const int* in_sizes, int n_in,
                              void* d_out, int out_size, void* d_ws, size_t ws_size,
                              hipStream_t stream)
{
    const float* emb  = (const float*)d_in[0];
    const int*   rows = (const int*)d_in[1];
    const int*   cols = (const int*)d_in[2];
    const float* vals = (const float*)d_in[3];
    const int*   node = (const int*)d_in[4];
    const int*   pos  = (const int*)d_in[5];
    const int*   neg  = (const int*)d_in[6];
    float* out = (float*)d_out;

    const int E = in_sizes[1];
    const int B = in_sizes[4];
    const int N = in_sizes[0] / 64;
    const size_t nd = (size_t)N * 64;
    const int nb = NB_SCAN(N);

    // workspace layout (bf16 feature buffers)
    ushort* aggA     = (ushort*)d_ws;              // N*64 bf16
    ushort* aggB     = aggA + nd;                  // N*64 bf16
    ushort* x0       = aggB + nd;                  // N*64 bf16 (emb cast)
    int2*  edges     = (int2*)(x0 + nd);           // E (8B each)
    int*   rank      = (int*)(edges + E);          // E
    int*   counts    = rank + E;                   // N
    int*   row_start = counts + N;                 // N+1
    int*   bsums     = row_start + N + 1;          // nb
    int*   bprefix   = bsums + nb;                 // nb

    const int gtotal  = 3 * B * 16;
    const int gblocks = (gtotal + 255) / 256;
    const int eblocks = (E + 255) / 256;
    const int rblocks = (N + 3) / 4;               // 4 rows (waves) per block
    const int cblocks = ((int)(nd / 4) + 255) / 256;

    init_out_k<<<gblocks, 256, 0, stream>>>(emb, node, pos, neg, out, B);
    f2bf_k<<<cblocks, 256, 0, stream>>>(emb, x0, (int)(nd / 4));

    // ---- CSR build ----
    hipMemsetAsync(counts, 0, (size_t)N * sizeof(int), stream);
    hist_rank_k<<<eblocks, 256, 0, stream>>>(rows, counts, rank, E);
    block_sums_k<<<nb, 256, 0, stream>>>(counts, bsums, N);
    scan_bsums_k<<<1, 512, 0, stream>>>(bsums, bprefix, nb);
    scan_counts_k<<<nb, 256, 0, stream>>>(counts, bprefix, row_start, N);
    scatter_k<<<eblocks, 256, 0, stream>>>(rows, cols, vals, rank, row_start, edges, E);

    // ---- 3 propagation hops, atomic-free, bf16 features ----
    spmm_csr_k<<<rblocks, 256, 0, stream>>>(row_start, edges, x0, aggA, N);
    gather_add_k<<<gblocks, 256, 0, stream>>>(aggA, node, pos, neg, out, B);

    spmm_csr_k<<<rblocks, 256, 0, stream>>>(row_start, edges, aggA, aggB, N);
    gather_add_k<<<gblocks, 256, 0, stream>>>(aggB, node, pos, neg, out, B);

    spmm_csr_k<<<rblocks, 256, 0, stream>>>(row_start, edges, aggB, aggA, N);
    gather_add_k<<<gblocks, 256, 0, stream>>>(aggA, node, pos, neg, out, B);
}